// Round 1
// baseline (233.911 us; speedup 1.0000x reference)
//
#include <hip/hip_runtime.h>
#include <stdint.h>

#define BPU    5
#define NBINS  200
#define GLEN   195   // NBINS - BPU
#define HLEN   196   // NBINS - BPU + 1
#define KH     256   // raw key-histogram bins
#define KOFF   128   // key offset: key = floor(x*5) + 128

// ---------------- helpers ----------------

// order-preserving float -> uint map (ascending)
__device__ inline uint32_t fkey(float f) {
    uint32_t u = __float_as_uint(f);
    return (u & 0x80000000u) ? ~u : (u | 0x80000000u);
}
__device__ inline float funkey(uint32_t k) {
    return (k & 0x80000000u) ? __uint_as_float(k ^ 0x80000000u)
                             : __uint_as_float(~k);
}

__device__ inline void bump(float v, uint32_t* lh) {
    float kf = floorf(v * 5.0f);
    kf = fminf(fmaxf(kf, (float)(-KOFF)), (float)(KH - 1 - KOFF));
    atomicAdd(&lh[(int)kf + KOFF], 1u);
}

// ---------------- kernel 0: init workspace (ws is re-poisoned every call) ----

__global__ __launch_bounds__(256) void k_init(uint32_t* khist, uint32_t* minkey, double* acc) {
    int t = threadIdx.x;
    khist[t] = 0u;                      // 256 bins
    if (t == 0) { *minkey = 0xFFFFFFFFu; *acc = 0.0; }
}

// ---------------- kernel 1: fused global-min + shifted histogram -------------

__global__ __launch_bounds__(256) void k_min_hist(const float4* __restrict__ x4, int n4,
                                                  const float* __restrict__ x, int n,
                                                  uint32_t* __restrict__ khist,
                                                  uint32_t* __restrict__ minkey) {
    __shared__ uint32_t lh[4][KH];      // one histogram copy per wave
    int t = threadIdx.x;
    int w = t >> 6;
    for (int j = t; j < 4 * KH; j += 256) ((uint32_t*)lh)[j] = 0u;
    __syncthreads();

    float lmin = 3.402823466e38f;
    int gid = blockIdx.x * 256 + t;
    int stride = gridDim.x * 256;
    for (int idx = gid; idx < n4; idx += stride) {
        float4 v = x4[idx];
        lmin = fminf(lmin, fminf(fminf(v.x, v.y), fminf(v.z, v.w)));
        bump(v.x, lh[w]); bump(v.y, lh[w]); bump(v.z, lh[w]); bump(v.w, lh[w]);
    }
    if (gid == 0) {                      // tail (none for this shape, but be general)
        for (int idx = n4 * 4; idx < n; ++idx) {
            float v = x[idx];
            lmin = fminf(lmin, v);
            bump(v, lh[w]);
        }
    }

    // block min reduction
    #pragma unroll
    for (int d = 32; d; d >>= 1) lmin = fminf(lmin, __shfl_down(lmin, d));
    __shared__ float wmin[4];
    if ((t & 63) == 0) wmin[w] = lmin;
    __syncthreads();

    // merge histogram copies -> global
    for (int j = t; j < KH; j += 256) {
        uint32_t s = lh[0][j] + lh[1][j] + lh[2][j] + lh[3][j];
        if (s) atomicAdd(&khist[j], s);
    }
    if (t == 0) {
        float m = fminf(fminf(wmin[0], wmin[1]), fminf(wmin[2], wmin[3]));
        atomicMin(minkey, fkey(m));
    }
}

// ---------------- kernel 2: build hist_add / g tables (1 block) --------------

__global__ __launch_bounds__(256) void k_tables(const uint32_t* __restrict__ khist,
                                                const uint32_t* __restrict__ minkey,
                                                float* __restrict__ g_tbl,
                                                float* __restrict__ ha_tbl,
                                                float* __restrict__ vmn_out,
                                                float fn) {
    __shared__ float cnt[KH];
    __shared__ float hist[NBINS];       // reused as inclusive cumsum after scan
    __shared__ float ha[HLEN];
    __shared__ int s_ivmin;
    int t = threadIdx.x;
    cnt[t] = (float)khist[t];
    if (t == 0) {
        float m = funkey(*minkey);
        float vmin = floorf(m) - 1.0f;  // integer-valued
        s_ivmin = (int)vmin;
    }
    __syncthreads();
    int base = KOFF + 5 * s_ivmin;      // key for reference bin 0

    if (t < NBINS) {
        float h = 0.0f;
        if (t == 0) {
            for (int kk = 0; kk < KH && kk <= base; ++kk) h += cnt[kk];
        } else if (t == NBINS - 1) {
            int lo = base + (NBINS - 1); if (lo < 0) lo = 0;
            for (int kk = lo; kk < KH; ++kk) h += cnt[kk];
        } else {
            int kk = base + t;
            if (kk >= 0 && kk < KH) h = cnt[kk];
        }
        hist[t] = h / fn;
    }
    __syncthreads();

    // inclusive Hillis-Steele scan over hist[0..199]
    for (int off = 1; off < NBINS; off <<= 1) {
        float v = 0.0f;
        if (t < NBINS && t >= off) v = hist[t - off];
        __syncthreads();
        if (t < NBINS && t >= off) hist[t] += v;
        __syncthreads();
    }

    if (t < HLEN) {
        float c_lo = (t == 0) ? 0.0f : hist[t - 1];
        ha[t] = hist[t + BPU - 1] - c_lo;   // c[t+5] - c[t]
    }
    __syncthreads();
    if (t < HLEN) ha_tbl[t] = ha[t];
    if (t < GLEN) g_tbl[t] = (ha[t + 1] - ha[t]) * 5.0f;
    if (t == 0)  *vmn_out = (float)s_ivmin + 0.5f;  // vmin_new
}

// ---------------- kernel 3: per-element loss + f64 reduction -----------------

__device__ inline double elem_loss(float v, float vmn,
                                   const float* __restrict__ sg,
                                   const float* __restrict__ sha) {
    int i = (int)floorf((v - vmn) * 5.0f);
    i = i < 0 ? 0 : (i > GLEN - 1 ? GLEN - 1 : i);
    float left = vmn + (float)i * 0.2f;
    float nl = (v - left) * sg[i] + sha[i] + 1e-8f;
    return (double)__logf(nl);
}

__global__ __launch_bounds__(256) void k_loss(const float4* __restrict__ x4, int n4,
                                              const float* __restrict__ x, int n,
                                              const float* __restrict__ g_tbl,
                                              const float* __restrict__ ha_tbl,
                                              const float* __restrict__ vmn_p,
                                              double* __restrict__ acc) {
    __shared__ float sg[GLEN];
    __shared__ float sha[HLEN];
    int t = threadIdx.x;
    if (t < GLEN) sg[t] = g_tbl[t];
    if (t < HLEN) sha[t] = ha_tbl[t];
    float vmn = vmn_p[0];
    __syncthreads();

    double s = 0.0;
    int gid = blockIdx.x * 256 + t;
    int stride = gridDim.x * 256;
    for (int idx = gid; idx < n4; idx += stride) {
        float4 v = x4[idx];
        s += elem_loss(v.x, vmn, sg, sha);
        s += elem_loss(v.y, vmn, sg, sha);
        s += elem_loss(v.z, vmn, sg, sha);
        s += elem_loss(v.w, vmn, sg, sha);
    }
    if (gid == 0) {
        for (int idx = n4 * 4; idx < n; ++idx) s += elem_loss(x[idx], vmn, sg, sha);
    }

    #pragma unroll
    for (int d = 32; d; d >>= 1) s += __shfl_down(s, d);
    __shared__ double wsum[4];
    if ((t & 63) == 0) wsum[t >> 6] = s;
    __syncthreads();
    if (t == 0) atomicAdd(acc, wsum[0] + wsum[1] + wsum[2] + wsum[3]);
}

// ---------------- kernel 4: finalize -----------------------------------------

__global__ void k_final(const double* __restrict__ acc, float* __restrict__ out, double inv_n) {
    // rloss = S / (-ln 2); out = rloss / n
    out[0] = (float)((*acc) * (-1.4426950408889634) * inv_n);
}

// ---------------- launch ------------------------------------------------------

extern "C" void kernel_launch(void* const* d_in, const int* in_sizes, int n_in,
                              void* d_out, int out_size, void* d_ws, size_t ws_size,
                              hipStream_t stream) {
    const float* x = (const float*)d_in[0];
    int n = in_sizes[0];
    int n4 = n >> 2;
    float* out = (float*)d_out;

    uint8_t* ws = (uint8_t*)d_ws;
    uint32_t* khist  = (uint32_t*)ws;            // 256 u32  [0,1024)
    uint32_t* minkey = (uint32_t*)(ws + 1024);
    double*   acc    = (double*)(ws + 1032);
    float*    vmn    = (float*)(ws + 1040);
    float*    g_tbl  = (float*)(ws + 1048);      // 195 f32 (padded to 200)
    float*    ha_tbl = (float*)(ws + 1848);      // 196 f32

    k_init<<<1, 256, 0, stream>>>(khist, minkey, acc);
    k_min_hist<<<1024, 256, 0, stream>>>((const float4*)x, n4, x, n, khist, minkey);
    k_tables<<<1, 256, 0, stream>>>(khist, minkey, g_tbl, ha_tbl, vmn, (float)n);
    k_loss<<<2048, 256, 0, stream>>>((const float4*)x, n4, x, n, g_tbl, ha_tbl, vmn, acc);
    k_final<<<1, 1, 0, stream>>>(acc, out, 1.0 / (double)n);
}